// Round 7
// baseline (128.483 us; speedup 1.0000x reference)
//
#include <hip/hip_runtime.h>
#include <hip/hip_bf16.h>
#include <math.h>

// ---------------- problem constants ----------------
#define M 8192
#define N 16384
#define D 64
#define ZC 58.81206612509905f        // 32*log(2*pi), h=1
#define B0 24.0f                     // exp2-domain bias (headroom; u<=0)
#define LOG2E 1.4426950408889634f
#define HL2E 0.7213475204444817f     // 0.5*log2(e)
#define LN2 0.6931471805599453f

// Schraudolph exp2: 2^u ~= bitcast(int(u*2^23 + (127 - 0.0435)*2^23)).
// Bias-corrected midpoint => max rel err ~±3% (log-output err <= 0.04,
// same order as existing bf16 dot noise; tolerance 0.5).
#define SCH_K 8388608.0f             // 2^23
#define SCH_C (1065353216.0f - 0.0435f * 8388608.0f)

#define PCH 16
#define NCHK (N / PCH)               // 1024 train cols per block

typedef short v8bf __attribute__((ext_vector_type(8)));   // 8 bf16 (4 VGPRs)
typedef float v16f __attribute__((ext_vector_type(16)));

// ws layout (bytes)
#define B_AU2  0                        // 8192 f32  (32 KB)
#define B_LW2  32768                    // 16384 f32 (64 KB)
#define B_PART 98304                    // 16*8192 f32 (512 KB), [chunk][m]
#define B_TB   622592                   // 8192*64 bf16 (1 MB)
#define B_TR   1671168                  // 16384*64 bf16 (2 MB)

// Fused prep: blocks 0..255 convert testX -> bf16(log2e*x) + au2;
// blocks 256..767 convert trainX -> bf16 + lw2 = log2(w) - hl2e*r2 + B0.
__global__ __launch_bounds__(256) void gk_prep(const float* __restrict__ testX,
                                               const float* __restrict__ trainX,
                                               const float* __restrict__ sw,
                                               __hip_bfloat16* __restrict__ tb,
                                               __hip_bfloat16* __restrict__ rb,
                                               float* __restrict__ au2,
                                               float* __restrict__ lw2) {
    const int tid = threadIdx.x;
    const int e = tid & 7;
    if (blockIdx.x < M / 32) {
        const int row = blockIdx.x * 32 + (tid >> 3);
        const float4* p = reinterpret_cast<const float4*>(testX + (size_t)row * D + e * 8);
        float4 v0 = p[0], v1 = p[1];
        float t2 = v0.x * v0.x + v0.y * v0.y + v0.z * v0.z + v0.w * v0.w
                 + v1.x * v1.x + v1.y * v1.y + v1.z * v1.z + v1.w * v1.w;
        t2 += __shfl_xor(t2, 1, 64);
        t2 += __shfl_xor(t2, 2, 64);
        t2 += __shfl_xor(t2, 4, 64);
        if (e == 0) au2[row] = -HL2E * t2;
        union { __hip_bfloat16 h[8]; uint4 u; } cv;
        cv.h[0] = __float2bfloat16(v0.x * LOG2E);
        cv.h[1] = __float2bfloat16(v0.y * LOG2E);
        cv.h[2] = __float2bfloat16(v0.z * LOG2E);
        cv.h[3] = __float2bfloat16(v0.w * LOG2E);
        cv.h[4] = __float2bfloat16(v1.x * LOG2E);
        cv.h[5] = __float2bfloat16(v1.y * LOG2E);
        cv.h[6] = __float2bfloat16(v1.z * LOG2E);
        cv.h[7] = __float2bfloat16(v1.w * LOG2E);
        *reinterpret_cast<uint4*>(tb + (size_t)row * D + e * 8) = cv.u;
    } else {
        const int row = (blockIdx.x - M / 32) * 32 + (tid >> 3);
        const float4* p = reinterpret_cast<const float4*>(trainX + (size_t)row * D + e * 8);
        float4 v0 = p[0], v1 = p[1];
        float r2 = v0.x * v0.x + v0.y * v0.y + v0.z * v0.z + v0.w * v0.w
                 + v1.x * v1.x + v1.y * v1.y + v1.z * v1.z + v1.w * v1.w;
        r2 += __shfl_xor(r2, 1, 64);
        r2 += __shfl_xor(r2, 2, 64);
        r2 += __shfl_xor(r2, 4, 64);
        if (e == 0) lw2[row] = __builtin_amdgcn_logf(sw[row]) - HL2E * r2 + B0;
        union { __hip_bfloat16 h[8]; uint4 u; } cv;
        cv.h[0] = __float2bfloat16(v0.x);
        cv.h[1] = __float2bfloat16(v0.y);
        cv.h[2] = __float2bfloat16(v0.z);
        cv.h[3] = __float2bfloat16(v0.w);
        cv.h[4] = __float2bfloat16(v1.x);
        cv.h[5] = __float2bfloat16(v1.y);
        cv.h[6] = __float2bfloat16(v1.z);
        cv.h[7] = __float2bfloat16(v1.w);
        *reinterpret_cast<uint4*>(rb + (size_t)row * D + e * 8) = cv.u;
    }
}

// Main: 128 test rows x 1024 train cols per block, 256 threads (4 waves),
// each wave owns 32 rows. NO LDS staging, NO main-loop barriers, NO DMA.
// B-fragments are read directly from global (the 128 KB rb chunk is
// L2-resident on this XCD; re-reads hit L1/L2). The fragment
//   rb[(n0 + t*64 + s*32 + c)*64 + (2q+h)*8]
// is bit-identical to what the LDS path delivered, so MFMA operands are
// unchanged. Each wave is an autonomous load->MFMA->accumulate pipeline
// (compiler software-pipelines it; 16 independent waves/CU give TLP).
// This directly tests the hypothesis that the ~38 us plateau was
// barrier-rendezvous serialization, since every issue-pipe floor is ~10 us.
// LDS: only the 16.9 KB epilogue reduction. Grid 64*16 = 1024 = 4/CU.
__global__ __launch_bounds__(256, 4) void gk_main(const __hip_bfloat16* __restrict__ ta,
                                                  const __hip_bfloat16* __restrict__ tr,
                                                  const float* __restrict__ lw2,
                                                  float* __restrict__ part) {
    __shared__ __align__(16) float red[128 * 33];   // 16896 B epilogue reduction
    const int tid = threadIdx.x;
    const int w = tid >> 6;
    const int lane = tid & 63;
    const int c = lane & 31;
    const int h = lane >> 5;

    // XCD swizzle: xcd = bid&7 owns chunks 2x..2x+1 (2048 train rows L2-local)
    const int bid = blockIdx.x;
    const int xcd = bid & 7;
    const int j = bid >> 3;                 // 0..127
    const int chunk = xcd * 2 + (j & 1);    // 0..15
    const int m0 = (j >> 1) * 128;          // 64 m-tiles
    const int n0 = chunk * NCHK;

    // A fragments: per-wave constant, 32 test rows
    const __hip_bfloat16* arow = ta + (size_t)(m0 + w * 32 + c) * D;
    v8bf af[4];
#pragma unroll
    for (int t = 0; t < 4; ++t)
        af[t] = *reinterpret_cast<const v8bf*>(arow + (2 * t + h) * 8);

    v16f zacc;
#pragma unroll
    for (int r = 0; r < 16; ++r) zacc[r] = 0.f;
    float srun[16];
#pragma unroll
    for (int r = 0; r < 16; ++r) srun[r] = 0.f;

    // lane's B row base: row (n0 + c), k-offset h*8; row stride D=64 bf16
    const __hip_bfloat16* bp0 = tr + (size_t)(n0 + c) * D + h * 8;
    const float* lwp = lw2 + n0 + c;

#pragma unroll 2
    for (int t = 0; t < 16; ++t) {
#pragma unroll
        for (int s = 0; s < 2; ++s) {
            const float lwv = lwp[t * 64 + s * 32];
            const float cs = fmaf(lwv, SCH_K, SCH_C);
            const __hip_bfloat16* bp = bp0 + (size_t)(t * 64 + s * 32) * D;
            v16f acc = __builtin_amdgcn_mfma_f32_32x32x16_bf16(
                af[0], *reinterpret_cast<const v8bf*>(bp), zacc, 0, 0, 0);
#pragma unroll
            for (int q = 1; q < 4; ++q)
                acc = __builtin_amdgcn_mfma_f32_32x32x16_bf16(
                    af[q], *reinterpret_cast<const v8bf*>(bp + q * 16), acc, 0, 0, 0);
#pragma unroll
            for (int r = 0; r < 16; ++r) {
                float tv = fmaf(acc[r], SCH_K, cs);
                tv = fmaxf(tv, 0.0f);
                srun[r] += __int_as_float((int)tv);
            }
        }
    }

    // ---- cross-lane row sum (cols live across 32 lanes) ----
#pragma unroll
    for (int r = 0; r < 16; ++r) {
        int rowl = (r & 3) + 8 * (r >> 2) + 4 * h;
        red[(w * 32 + rowl) * 33 + c] = srun[r];
    }
    __syncthreads();
    if (tid < 128) {
        float G = 0.f;
#pragma unroll
        for (int c2 = 0; c2 < 32; ++c2) G += red[tid * 33 + c2];
        part[(size_t)chunk * M + m0 + tid] = G;   // [chunk][m] coalesced
    }
}

__global__ __launch_bounds__(256) void gk_merge(const float* __restrict__ part,
                                                const float* __restrict__ au2,
                                                const float* __restrict__ sw,
                                                float* __restrict__ out) {
    __shared__ float red[256];
    const int tid = threadIdx.x;
    // W = sum(sw), recomputed per block (64 KB, L2-resident, fully parallel)
    float s = 0.f;
    const float4* p4 = reinterpret_cast<const float4*>(sw);
    for (int i = tid; i < N / 4; i += 256) {
        float4 v = p4[i];
        s += v.x + v.y + v.z + v.w;
    }
    red[tid] = s;
    __syncthreads();
    for (int off = 128; off > 0; off >>= 1) {
        if (tid < off) red[tid] += red[tid + off];
        __syncthreads();
    }
    const float W = red[0];

    const int r = blockIdx.x * 256 + tid;
    float G = 0.f;
#pragma unroll
    for (int p = 0; p < PCH; ++p) G += part[(size_t)p * M + r];
    out[r] = LN2 * (au2[r] + __builtin_amdgcn_logf(fmaxf(G, 1e-30f)) - B0
                   - __builtin_amdgcn_logf(W)) - ZC;
}

extern "C" void kernel_launch(void* const* d_in, const int* in_sizes, int n_in,
                              void* d_out, int out_size, void* d_ws, size_t ws_size,
                              hipStream_t stream) {
    const float* testX  = (const float*)d_in[0];   // [8192, 64]
    const float* trainX = (const float*)d_in[1];   // [16384, 64]
    const float* sw     = (const float*)d_in[2];   // [16384]
    float* out = (float*)d_out;                    // [8192]
    char* wsb = (char*)d_ws;

    float* au2  = (float*)(wsb + B_AU2);
    float* lw2  = (float*)(wsb + B_LW2);
    float* part = (float*)(wsb + B_PART);
    __hip_bfloat16* tb = (__hip_bfloat16*)(wsb + B_TB);
    __hip_bfloat16* rb = (__hip_bfloat16*)(wsb + B_TR);

    gk_prep<<<M / 32 + N / 32, 256, 0, stream>>>(testX, trainX, sw, tb, rb, au2, lw2);
    gk_main<<<(M / 128) * PCH, 256, 0, stream>>>(tb, rb, lw2, part);
    gk_merge<<<M / 256, 256, 0, stream>>>(part, au2, sw, out);
}